// Round 9
// baseline (211.142 us; speedup 1.0000x reference)
//
#include <hip/hip_runtime.h>
#include <cstdint>
#include <cstddef>

#define N_NODES 50000
#define N_EDGES 800000
#define D 512
#define M_PAD 50048   // 391 * 128

typedef __bf16 bf16x8 __attribute__((ext_vector_type(8)));
typedef float floatx4 __attribute__((ext_vector_type(4)));

typedef const __attribute__((address_space(1))) unsigned int* gas_u32p;
typedef __attribute__((address_space(3))) unsigned int* las_u32p;

__device__ __forceinline__ unsigned short f2bf(float f) {
    unsigned int u = __builtin_bit_cast(unsigned int, f);
    u += 0x7FFFu + ((u >> 16) & 1u);
    return (unsigned short)(u >> 16);
}
__device__ __forceinline__ float bflo(unsigned int u) {
    return __builtin_bit_cast(float, u << 16);
}
__device__ __forceinline__ float bfhi(unsigned int u) {
    return __builtin_bit_cast(float, u & 0xFFFF0000u);
}
__device__ __forceinline__ bf16x8 cvt8f(floatx4 lo, floatx4 hi) {
    bf16x8 r;
    r[0] = (__bf16)lo[0]; r[1] = (__bf16)lo[1]; r[2] = (__bf16)lo[2]; r[3] = (__bf16)lo[3];
    r[4] = (__bf16)hi[0]; r[5] = (__bf16)hi[1]; r[6] = (__bf16)hi[2]; r[7] = (__bf16)hi[3];
    return r;
}

// ---- fused prep: blocks [0,1024) convert W -> WT bf16; blocks [1024,1220) rowptr ----
__global__ __launch_bounds__(256) void k_prep(const float* __restrict__ w,
                                              unsigned short* __restrict__ wt,
                                              const int* __restrict__ rows,
                                              int* __restrict__ rp) {
    int blk = blockIdx.x;
    if (blk < 1024) {
        int id = blk * 256 + threadIdx.x;   // 262144 total, exact
        int n = id >> 9, k = id & 511;
        wt[id] = f2bf(w[k * D + n]);
    } else {
        int i = (blk - 1024) * 256 + threadIdx.x;
        if (i > N_NODES) return;
        int lo = 0, hi = N_EDGES;
        while (lo < hi) {
            int mid = (lo + hi) >> 1;
            if (rows[mid] < i) lo = mid + 1; else hi = mid;
        }
        rp[i] = lo;
    }
}

// ---- H = (U_f32 @ W) in bf16.
// R9: A stays via global_load_lds f32 -> LDS (R4-proven coalescing); B fragments
// load DIRECT from WT to registers (R6's pB mapping, which was correct): per
// fragment-instr the wave touches 16 rows x one 64B line (4 quads share a line)
// from the L2-hot 128 KB WT nt-slice. Removes all B LDS traffic (24 KB/step of
// the 72) and B's gload_lds. bfr loads issue between the barriers so their L2
// latency drains in the same window as the A-stage vmcnt.
// LB(256,4): 4 blocks/CU resident (R8, +6 us) hides per-step barrier drains.
// A source chunk XOR-swizzled (c = slot^(m&7)), LDS linear, read with same XOR
// (both-sides-or-neither, rule 21). Tail rows clamp to 49999 (never read).
__global__ __launch_bounds__(256, 4) void k_gemm(const float* __restrict__ Af,
                                                 const unsigned short* __restrict__ WT,
                                                 unsigned short* __restrict__ H) {
    __shared__ float lAf[128 * 32];   // 16 KB (A only)
    int b = blockIdx.x;                 // 1564 = 391 * 4
    int mt, nt;
    if (b < 1536) {                     // 48 groups of (8 m-tiles x 4 n-tiles)
        mt = (b >> 5) * 8 + (b & 7);
        nt = (b >> 3) & 3;
    } else {                            // tail: 7 m-tiles x 4 n-tiles
        int r = b - 1536;
        mt = 384 + (r % 7);
        nt = r / 7;
    }
    const int tid  = threadIdx.x;
    const int wave = tid >> 6, lane = tid & 63;
    const int tileM0 = mt * 128;
    const int tileN0 = nt * 128;
    const int wr = wave >> 1, wc = wave & 1;
    const int quad = lane >> 4, half = lane & 15;

    // A staging: 4 global_load_lds per wave, each covers 8 rows (1 KB).
    const int lrowA  = lane >> 3;
    const int lslotA = lane & 7;
    int asrc[4];
#pragma unroll
    for (int g = 0; g < 4; g++) {
        int m  = wave * 32 + g * 8 + lrowA;
        int gm = tileM0 + m;
        if (gm > N_NODES - 1) gm = N_NODES - 1;
        int c = lslotA ^ (m & 7);
        asrc[g] = gm * D + c * 4;          // float index (k0 added in-loop)
    }

    // B fragment pointers: direct from WT (L2-hot), R6-verified mapping
    const unsigned short* pB[4];
#pragma unroll
    for (int j = 0; j < 4; j++) {
        int gn = tileN0 + wc * 64 + j * 16 + half;
        pB[j] = WT + (size_t)gn * D + quad * 8;
    }

    floatx4 acc[4][4] = {};

    int offAlo[4], offAhi[4];
#pragma unroll
    for (int i = 0; i < 4; i++) {
        int m = wr * 64 + i * 16 + half;        // m&7 == half&7
        offAlo[i] = m * 32 + (((quad * 2)     ^ (m & 7)) * 4);
        offAhi[i] = m * 32 + (((quad * 2 + 1) ^ (m & 7)) * 4);
    }

    for (int k0 = 0; k0 < D; k0 += 32) {
        __syncthreads();   // previous iteration's ds_reads complete
#pragma unroll
        for (int g = 0; g < 4; g++)
            __builtin_amdgcn_global_load_lds((gas_u32p)(Af + asrc[g] + k0),
                                             (las_u32p)(lAf + (wave * 32 + g * 8) * 32), 16, 0, 0);
        bf16x8 bfr[4];
#pragma unroll
        for (int j = 0; j < 4; j++)
            bfr[j] = *(const bf16x8*)(pB[j] + k0);
        __syncthreads();   // drains vmcnt: A in LDS, bfr in regs

        bf16x8 af[4];
#pragma unroll
        for (int i = 0; i < 4; i++) {
            floatx4 lo = *(const floatx4*)(lAf + offAlo[i]);
            floatx4 hi = *(const floatx4*)(lAf + offAhi[i]);
            af[i] = cvt8f(lo, hi);
        }
#pragma unroll
        for (int i = 0; i < 4; i++)
#pragma unroll
            for (int j = 0; j < 4; j++)
                acc[i][j] = __builtin_amdgcn_mfma_f32_16x16x32_bf16(af[i], bfr[j], acc[i][j], 0, 0, 0);
    }

    // epilogue: C/D layout col = lane&15, row = quad*4 + r (row-major H)
#pragma unroll
    for (int i = 0; i < 4; i++) {
        int gm0 = tileM0 + wr * 64 + i * 16 + quad * 4;
#pragma unroll
        for (int j = 0; j < 4; j++) {
            int gn = tileN0 + wc * 64 + j * 16 + half;
#pragma unroll
            for (int r = 0; r < 4; r++) {
                H[(size_t)(gm0 + r) * D + gn] = f2bf(acc[i][j][r]);
            }
        }
    }
}

// ---- out[row] = relu( sum_e vals[e] * h[cols[e]] ), one wave per node.
// PROVEN FLAT STRUCTURE (125.7-126.1 us) -- final. 1 KB-row burst gathers are
// the efficient pattern: unroll-8 null (R2), col-slicing 3.5x worse (R7).
// FETCH ~380 MB = 8-XCD replication floor; delivered-byte throughput bound.
__global__ __launch_bounds__(256) void k_scatter(const int* __restrict__ rp,
                                                 const int* __restrict__ cols,
                                                 const float* __restrict__ vals,
                                                 const unsigned short* __restrict__ H,
                                                 float* __restrict__ out) {
    int node = (int)((blockIdx.x * 256 + threadIdx.x) >> 6);
    int lane = threadIdx.x & 63;
    if (node >= N_NODES) return;
    int s = rp[node], e = rp[node + 1];
    float a0 = 0.f, a1 = 0.f, a2 = 0.f, a3 = 0.f;
    float a4 = 0.f, a5 = 0.f, a6 = 0.f, a7 = 0.f;
    const uint4* H4 = (const uint4*)H;          // row c starts at index c*64
    const int lq = lane;                        // uint4 slot within row
    for (int t = s; t < e; t += 4) {
        int last = e - 1;
        int t1 = t + 1 < e ? t + 1 : last;
        int t2 = t + 2 < e ? t + 2 : last;
        int t3 = t + 3 < e ? t + 3 : last;
        int c0 = cols[t],  c1 = cols[t1], c2 = cols[t2], c3 = cols[t3];
        float v0 = vals[t];
        float v1 = t + 1 < e ? vals[t1] : 0.f;
        float v2 = t + 2 < e ? vals[t2] : 0.f;
        float v3 = t + 3 < e ? vals[t3] : 0.f;
        uint4 d0 = H4[(size_t)c0 * 64 + lq];
        uint4 d1 = H4[(size_t)c1 * 64 + lq];
        uint4 d2 = H4[(size_t)c2 * 64 + lq];
        uint4 d3 = H4[(size_t)c3 * 64 + lq];
        a0 = fmaf(v0, bflo(d0.x), a0); a1 = fmaf(v0, bfhi(d0.x), a1);
        a2 = fmaf(v0, bflo(d0.y), a2); a3 = fmaf(v0, bfhi(d0.y), a3);
        a4 = fmaf(v0, bflo(d0.z), a4); a5 = fmaf(v0, bfhi(d0.z), a5);
        a6 = fmaf(v0, bflo(d0.w), a6); a7 = fmaf(v0, bfhi(d0.w), a7);
        a0 = fmaf(v1, bflo(d1.x), a0); a1 = fmaf(v1, bfhi(d1.x), a1);
        a2 = fmaf(v1, bflo(d1.y), a2); a3 = fmaf(v1, bfhi(d1.y), a3);
        a4 = fmaf(v1, bflo(d1.z), a4); a5 = fmaf(v1, bfhi(d1.z), a5);
        a6 = fmaf(v1, bflo(d1.w), a6); a7 = fmaf(v1, bfhi(d1.w), a7);
        a0 = fmaf(v2, bflo(d2.x), a0); a1 = fmaf(v2, bfhi(d2.x), a1);
        a2 = fmaf(v2, bflo(d2.y), a2); a3 = fmaf(v2, bfhi(d2.y), a3);
        a4 = fmaf(v2, bflo(d2.z), a4); a5 = fmaf(v2, bfhi(d2.z), a5);
        a6 = fmaf(v2, bflo(d2.w), a6); a7 = fmaf(v2, bfhi(d2.w), a7);
        a0 = fmaf(v3, bflo(d3.x), a0); a1 = fmaf(v3, bfhi(d3.x), a1);
        a2 = fmaf(v3, bflo(d3.y), a2); a3 = fmaf(v3, bfhi(d3.y), a3);
        a4 = fmaf(v3, bflo(d3.z), a4); a5 = fmaf(v3, bfhi(d3.z), a5);
        a6 = fmaf(v3, bflo(d3.w), a6); a7 = fmaf(v3, bfhi(d3.w), a7);
    }
    float* o = out + (size_t)node * D + (size_t)lane * 8;
    *(float4*)o       = make_float4(fmaxf(a0, 0.f), fmaxf(a1, 0.f), fmaxf(a2, 0.f), fmaxf(a3, 0.f));
    *(float4*)(o + 4) = make_float4(fmaxf(a4, 0.f), fmaxf(a5, 0.f), fmaxf(a6, 0.f), fmaxf(a7, 0.f));
}

extern "C" void kernel_launch(void* const* d_in, const int* in_sizes, int n_in,
                              void* d_out, int out_size, void* d_ws, size_t ws_size,
                              hipStream_t stream) {
    const int*   adj_rows = (const int*)d_in[0];
    const int*   adj_cols = (const int*)d_in[1];
    const float* adj_vals = (const float*)d_in[2];
    const float* u_f      = (const float*)d_in[3];
    const float* weight   = (const float*)d_in[4];
    float* out = (float*)d_out;

    char* ws = (char*)d_ws;
    unsigned short* wt_bf = (unsigned short*)ws;                       // 524,288 B
    unsigned short* h_bf  = (unsigned short*)(ws + 524288);            // 51,249,152 B
    int* rowptr           = (int*)(ws + 524288 + 51249152);            // 200,004 B

    hipLaunchKernelGGL(k_prep,    dim3(1220),  dim3(256), 0, stream, weight, wt_bf, adj_rows, rowptr);
    hipLaunchKernelGGL(k_gemm,    dim3(1564),  dim3(256), 0, stream, u_f, wt_bf, h_bf);
    hipLaunchKernelGGL(k_scatter, dim3(12500), dim3(256), 0, stream, rowptr, adj_cols, adj_vals, h_bf, out);
}

// Round 10
// 185.626 us; speedup vs baseline: 1.1375x; 1.1375x over previous
//
#include <hip/hip_runtime.h>
#include <cstdint>
#include <cstddef>

#define N_NODES 50000
#define N_EDGES 800000
#define D 512
#define M_PAD 50048   // 391 * 128

typedef __bf16 bf16x8 __attribute__((ext_vector_type(8)));
typedef float floatx4 __attribute__((ext_vector_type(4)));

typedef const __attribute__((address_space(1))) unsigned int* gas_u32p;
typedef __attribute__((address_space(3))) unsigned int* las_u32p;

__device__ __forceinline__ unsigned short f2bf(float f) {
    unsigned int u = __builtin_bit_cast(unsigned int, f);
    u += 0x7FFFu + ((u >> 16) & 1u);
    return (unsigned short)(u >> 16);
}
__device__ __forceinline__ float bflo(unsigned int u) {
    return __builtin_bit_cast(float, u << 16);
}
__device__ __forceinline__ float bfhi(unsigned int u) {
    return __builtin_bit_cast(float, u & 0xFFFF0000u);
}
__device__ __forceinline__ bf16x8 cvt8f(floatx4 lo, floatx4 hi) {
    bf16x8 r;
    r[0] = (__bf16)lo[0]; r[1] = (__bf16)lo[1]; r[2] = (__bf16)lo[2]; r[3] = (__bf16)lo[3];
    r[4] = (__bf16)hi[0]; r[5] = (__bf16)hi[1]; r[6] = (__bf16)hi[2]; r[7] = (__bf16)hi[3];
    return r;
}

// ---- fused prep: blocks [0,1024) convert W -> WT bf16; blocks [1024,1220) rowptr ----
__global__ __launch_bounds__(256) void k_prep(const float* __restrict__ w,
                                              unsigned short* __restrict__ wt,
                                              const int* __restrict__ rows,
                                              int* __restrict__ rp) {
    int blk = blockIdx.x;
    if (blk < 1024) {
        int id = blk * 256 + threadIdx.x;   // 262144 total, exact
        int n = id >> 9, k = id & 511;
        wt[id] = f2bf(w[k * D + n]);
    } else {
        int i = (blk - 1024) * 256 + threadIdx.x;
        if (i > N_NODES) return;
        int lo = 0, hi = N_EDGES;
        while (lo < hi) {
            int mid = (lo + hi) >> 1;
            if (rows[mid] < i) lo = mid + 1; else hi = mid;
        }
        rp[i] = lo;
    }
}

// ---- H = (U_f32 @ W) in bf16, A converted f32->bf16 on the LDS read.
// R10: A DOUBLE-BUFFERED (2x16 KB f32), B single-buffered but staged one
// compute-phase ahead (issued after barrier-2 when the B buffer is free).
// LDS = 40 KB -> still 4 blocks/CU (R5's full-dbuf 48 KB dropped to 3 -> null).
// Counted vmcnt(4): at the wait, outstanding = A(k)4 + B(k)2 + A(k+1)4 = 10;
// retire cur's 6, keep next-A in flight. Never drain to 0 mid-loop (T4).
// R9 lesson: B-direct from WT regressed (16 line-req/instr in TA) -> B stays
// LDS-staged. LB(256,4): 4 blocks/CU (R8, +6 us). A source chunk XOR-swizzled
// (c = slot^(m&7)), LDS linear, read with same XOR (rule 21). Tail rows clamp
// to 49999 (their H rows are never read: cols < 50000).
__global__ __launch_bounds__(256, 4) void k_gemm(const float* __restrict__ Af,
                                                 const unsigned short* __restrict__ WT,
                                                 unsigned short* __restrict__ H) {
    __shared__ float          lAf[2 * 128 * 32];   // 32 KB (dbuf)
    __shared__ unsigned short lB [128 * 32];       // 8 KB  (single)
    int b = blockIdx.x;                 // 1564 = 391 * 4
    int mt, nt;
    if (b < 1536) {                     // 48 groups of (8 m-tiles x 4 n-tiles)
        mt = (b >> 5) * 8 + (b & 7);
        nt = (b >> 3) & 3;
    } else {                            // tail: 7 m-tiles x 4 n-tiles
        int r = b - 1536;
        mt = 384 + (r % 7);
        nt = r / 7;
    }
    const int tid  = threadIdx.x;
    const int wave = tid >> 6, lane = tid & 63;
    const int tileM0 = mt * 128;
    const int tileN0 = nt * 128;
    const int wr = wave >> 1, wc = wave & 1;

    // A staging: 4 global_load_lds per wave, each covers 8 rows (1 KB).
    const int lrowA  = lane >> 3;
    const int lslotA = lane & 7;
    int asrc[4];
#pragma unroll
    for (int g = 0; g < 4; g++) {
        int m  = wave * 32 + g * 8 + lrowA;
        int gm = tileM0 + m;
        if (gm > N_NODES - 1) gm = N_NODES - 1;
        int c = lslotA ^ (m & 7);
        asrc[g] = gm * D + c * 4;          // float index (k0 added in-loop)
    }

    // B staging: bf16, chunk-rotated rows of 64 B (R0-proven)
    const int lrowB = lane >> 2, lslotB = lane & 3;
    const int r0 = wave * 32;
    const int m0 = r0 + lrowB,      m1 = r0 + 16 + lrowB;
    const int q0 = (lslotB - (m0 >> 1)) & 3;
    const int q1 = (lslotB - (m1 >> 1)) & 3;
    const unsigned short* gB0 = WT + (size_t)(tileN0 + m0) * D + q0 * 8;
    const unsigned short* gB1 = WT + (size_t)(tileN0 + m1) * D + q1 * 8;
    unsigned short* lB0 = lB + r0 * 32;
    unsigned short* lB1 = lB + (r0 + 16) * 32;

    floatx4 acc[4][4] = {};

    const int quad = lane >> 4, half = lane & 15;
    int offAlo[4], offAhi[4], offB[4];
#pragma unroll
    for (int i = 0; i < 4; i++) {
        int m = wr * 64 + i * 16 + half;        // m&7 == half&7
        offAlo[i] = m * 32 + (((quad * 2)     ^ (m & 7)) * 4);
        offAhi[i] = m * 32 + (((quad * 2 + 1) ^ (m & 7)) * 4);
        int n = wc * 64 + i * 16 + half;
        offB[i] = n * 32 + ((quad + (n >> 1)) & 3) * 8;
    }

    auto stageA = [&](int buf, int k0) {
        float* dA = lAf + buf * 4096;
#pragma unroll
        for (int g = 0; g < 4; g++)
            __builtin_amdgcn_global_load_lds((gas_u32p)(Af + asrc[g] + k0),
                                             (las_u32p)(dA + (wave * 32 + g * 8) * 32), 16, 0, 0);
    };
    auto stageB = [&](int k0) {
        __builtin_amdgcn_global_load_lds((gas_u32p)(gB0 + k0), (las_u32p)lB0, 16, 0, 0);
        __builtin_amdgcn_global_load_lds((gas_u32p)(gB1 + k0), (las_u32p)lB1, 16, 0, 0);
    };

    stageB(0);            // 2 loads (oldest)
    stageA(0, 0);         // 4 loads
    for (int kk = 0; kk < 16; kk++) {
        const int cur = kk & 1;
        if (kk < 15) {
            stageA(cur ^ 1, (kk + 1) * 32);    // 4 loads, stay in flight
            asm volatile("s_waitcnt vmcnt(4)" ::: "memory");   // retire A(k)+B(k)
        } else {
            asm volatile("s_waitcnt vmcnt(0)" ::: "memory");
        }
        __builtin_amdgcn_s_barrier();          // cur A + B resident for all waves

        const float* cA = lAf + cur * 4096;
        bf16x8 af[4], bfr[4];
#pragma unroll
        for (int i = 0; i < 4; i++) {
            floatx4 lo = *(const floatx4*)(cA + offAlo[i]);
            floatx4 hi = *(const floatx4*)(cA + offAhi[i]);
            af[i]  = cvt8f(lo, hi);
            bfr[i] = *(const bf16x8*)(lB + offB[i]);
        }
#pragma unroll
        for (int i = 0; i < 4; i++)
#pragma unroll
            for (int j = 0; j < 4; j++)
                acc[i][j] = __builtin_amdgcn_mfma_f32_16x16x32_bf16(af[i], bfr[j], acc[i][j], 0, 0, 0);

        asm volatile("s_waitcnt lgkmcnt(0)" ::: "memory");  // this wave's LDS reads done
        __builtin_amdgcn_s_barrier();          // B buffer (and A[cur]) now free
        if (kk < 15) stageB((kk + 1) * 32);    // 2 loads, one phase ahead
    }

    // epilogue: C/D layout col = lane&15, row = quad*4 + r (row-major H)
#pragma unroll
    for (int i = 0; i < 4; i++) {
        int gm0 = tileM0 + wr * 64 + i * 16 + quad * 4;
#pragma unroll
        for (int j = 0; j < 4; j++) {
            int gn = tileN0 + wc * 64 + j * 16 + half;
#pragma unroll
            for (int r = 0; r < 4; r++) {
                H[(size_t)(gm0 + r) * D + gn] = f2bf(acc[i][j][r]);
            }
        }
    }
}

// ---- out[row] = relu( sum_e vals[e] * h[cols[e]] ), one wave per node.
// PROVEN FLAT STRUCTURE (125-126 us) -- final. 1 KB-row burst gathers are the
// efficient pattern: unroll-8 null (R2), col-slicing 3.5x worse (R7).
// FETCH ~380 MB = 8-XCD replication floor; random-access HBM efficiency bound
// (3.9 TB/s combined ~ 60% of streaming-achievable; measured-stable x6 rounds).
__global__ __launch_bounds__(256) void k_scatter(const int* __restrict__ rp,
                                                 const int* __restrict__ cols,
                                                 const float* __restrict__ vals,
                                                 const unsigned short* __restrict__ H,
                                                 float* __restrict__ out) {
    int node = (int)((blockIdx.x * 256 + threadIdx.x) >> 6);
    int lane = threadIdx.x & 63;
    if (node >= N_NODES) return;
    int s = rp[node], e = rp[node + 1];
    float a0 = 0.f, a1 = 0.f, a2 = 0.f, a3 = 0.f;
    float a4 = 0.f, a5 = 0.f, a6 = 0.f, a7 = 0.f;
    const uint4* H4 = (const uint4*)H;          // row c starts at index c*64
    const int lq = lane;                        // uint4 slot within row
    for (int t = s; t < e; t += 4) {
        int last = e - 1;
        int t1 = t + 1 < e ? t + 1 : last;
        int t2 = t + 2 < e ? t + 2 : last;
        int t3 = t + 3 < e ? t + 3 : last;
        int c0 = cols[t],  c1 = cols[t1], c2 = cols[t2], c3 = cols[t3];
        float v0 = vals[t];
        float v1 = t + 1 < e ? vals[t1] : 0.f;
        float v2 = t + 2 < e ? vals[t2] : 0.f;
        float v3 = t + 3 < e ? vals[t3] : 0.f;
        uint4 d0 = H4[(size_t)c0 * 64 + lq];
        uint4 d1 = H4[(size_t)c1 * 64 + lq];
        uint4 d2 = H4[(size_t)c2 * 64 + lq];
        uint4 d3 = H4[(size_t)c3 * 64 + lq];
        a0 = fmaf(v0, bflo(d0.x), a0); a1 = fmaf(v0, bfhi(d0.x), a1);
        a2 = fmaf(v0, bflo(d0.y), a2); a3 = fmaf(v0, bfhi(d0.y), a3);
        a4 = fmaf(v0, bflo(d0.z), a4); a5 = fmaf(v0, bfhi(d0.z), a5);
        a6 = fmaf(v0, bflo(d0.w), a6); a7 = fmaf(v0, bfhi(d0.w), a7);
        a0 = fmaf(v1, bflo(d1.x), a0); a1 = fmaf(v1, bfhi(d1.x), a1);
        a2 = fmaf(v1, bflo(d1.y), a2); a3 = fmaf(v1, bfhi(d1.y), a3);
        a4 = fmaf(v1, bflo(d1.z), a4); a5 = fmaf(v1, bfhi(d1.z), a5);
        a6 = fmaf(v1, bflo(d1.w), a6); a7 = fmaf(v1, bfhi(d1.w), a7);
        a0 = fmaf(v2, bflo(d2.x), a0); a1 = fmaf(v2, bfhi(d2.x), a1);
        a2 = fmaf(v2, bflo(d2.y), a2); a3 = fmaf(v2, bfhi(d2.y), a3);
        a4 = fmaf(v2, bflo(d2.z), a4); a5 = fmaf(v2, bfhi(d2.z), a5);
        a6 = fmaf(v2, bflo(d2.w), a6); a7 = fmaf(v2, bfhi(d2.w), a7);
        a0 = fmaf(v3, bflo(d3.x), a0); a1 = fmaf(v3, bfhi(d3.x), a1);
        a2 = fmaf(v3, bflo(d3.y), a2); a3 = fmaf(v3, bfhi(d3.y), a3);
        a4 = fmaf(v3, bflo(d3.z), a4); a5 = fmaf(v3, bfhi(d3.z), a5);
        a6 = fmaf(v3, bflo(d3.w), a6); a7 = fmaf(v3, bfhi(d3.w), a7);
    }
    float* o = out + (size_t)node * D + (size_t)lane * 8;
    *(float4*)o       = make_float4(fmaxf(a0, 0.f), fmaxf(a1, 0.f), fmaxf(a2, 0.f), fmaxf(a3, 0.f));
    *(float4*)(o + 4) = make_float4(fmaxf(a4, 0.f), fmaxf(a5, 0.f), fmaxf(a6, 0.f), fmaxf(a7, 0.f));
}

extern "C" void kernel_launch(void* const* d_in, const int* in_sizes, int n_in,
                              void* d_out, int out_size, void* d_ws, size_t ws_size,
                              hipStream_t stream) {
    const int*   adj_rows = (const int*)d_in[0];
    const int*   adj_cols = (const int*)d_in[1];
    const float* adj_vals = (const float*)d_in[2];
    const float* u_f      = (const float*)d_in[3];
    const float* weight   = (const float*)d_in[4];
    float* out = (float*)d_out;

    char* ws = (char*)d_ws;
    unsigned short* wt_bf = (unsigned short*)ws;                       // 524,288 B
    unsigned short* h_bf  = (unsigned short*)(ws + 524288);            // 51,249,152 B
    int* rowptr           = (int*)(ws + 524288 + 51249152);            // 200,004 B

    hipLaunchKernelGGL(k_prep,    dim3(1220),  dim3(256), 0, stream, weight, wt_bf, adj_rows, rowptr);
    hipLaunchKernelGGL(k_gemm,    dim3(1564),  dim3(256), 0, stream, u_f, wt_bf, h_bf);
    hipLaunchKernelGGL(k_scatter, dim3(12500), dim3(256), 0, stream, rowptr, adj_cols, adj_vals, h_bf, out);
}